// Round 3
// baseline (80.468 us; speedup 1.0000x reference)
//
#include <hip/hip_runtime.h>
#include <hip/hip_bf16.h>
#include <math.h>

#define T_LEN    2400
#define NTAPS    16
#define FRAME    160
#define NFRAMES  15
#define OPT      8                       // outputs per thread (8 divides FRAME -> uniform frame)
#define CHUNKS   (T_LEN / OPT)           // 300 chunks per row
#define SCALE_C    (255.0f / 32768.0f)
#define SCALE_1_C  (32768.0f / 255.0f)

// u2l: s * (32768/255) * (2^(|u|/16) - 1)
__device__ __forceinline__ float u2l_f(float uv) {
    float u = uv - 128.0f;
    float a = fabsf(u);
    float m = SCALE_1_C * (exp2f(a * 0.0625f) - 1.0f);
    return copysignf(m, u);
}

// l2u: clip(128 + s*16*log2(1 + SCALE*|x|), 0, 255)
__device__ __forceinline__ float l2u_f(float x) {
    float a = fabsf(x);
    float u = 16.0f * log2f(fmaf(SCALE_C, a, 1.0f));
    u = copysignf(u, x);
    float r = 128.0f + u;
    return fminf(fmaxf(r, 0.0f), 255.0f);
}

__global__ __launch_bounds__(256) void diff_pred_kernel(
        const float* __restrict__ sig,
        const float* __restrict__ lpc,
        float* __restrict__ out) {
    const int gid = blockIdx.x * 256 + threadIdx.x;     // flat (row, chunk) index
    const int row = gid / CHUNKS;
    const int c   = gid - row * CHUNKS;                 // chunk in row, t0 = 8*c
    const int t0  = c * OPT;

    const float* sig_r = sig + (size_t)row * T_LEN;
    const float* lpc_r = lpc + (size_t)row * (NFRAMES * NTAPS);
    float*       out_r = out + (size_t)row * T_LEN;

    // coefficients for this chunk's frame (uniform across the 8 outputs)
    const int f = c / 20;                               // == t0 / FRAME
    const float4 c0 = *(const float4*)&lpc_r[f * NTAPS + 0];
    const float4 c1 = *(const float4*)&lpc_r[f * NTAPS + 4];
    const float4 c2 = *(const float4*)&lpc_r[f * NTAPS + 8];
    const float4 c3 = *(const float4*)&lpc_r[f * NTAPS + 12];
    const float cf[NTAPS] = {c0.x, c0.y, c0.z, c0.w, c1.x, c1.y, c1.z, c1.w,
                             c2.x, c2.y, c2.z, c2.w, c3.x, c3.y, c3.z, c3.w};

    // decoded window w[m] = xt[t0 - 16 + m], m = 0..23 (zeros for t < 0)
    float w[24];
    if (c >= 2) {
        // t0-16 = 8*(c-2) floats -> 32B aligned; 6 x float4 global loads
        const float4* p = (const float4*)(sig_r + t0 - NTAPS);
        #pragma unroll
        for (int q = 0; q < 6; ++q) {
            float4 v = p[q];
            w[4 * q + 0] = u2l_f(v.x);
            w[4 * q + 1] = u2l_f(v.y);
            w[4 * q + 2] = u2l_f(v.z);
            w[4 * q + 3] = u2l_f(v.w);
        }
    } else {
        #pragma unroll
        for (int m = 0; m < 24; ++m) {
            const int t = t0 - NTAPS + m;
            w[m] = (t >= 0) ? u2l_f(sig_r[t]) : 0.0f;
        }
    }

    // out[t0+k] = l2u(-sum_j cf[j] * xt[t0+k-j]),  xt[t0+k-j] = w[16+k-j]
    float acc[OPT];
    #pragma unroll
    for (int k = 0; k < OPT; ++k) acc[k] = 0.0f;
    #pragma unroll
    for (int j = 0; j < NTAPS; ++j) {
        #pragma unroll
        for (int k = 0; k < OPT; ++k) {
            acc[k] = fmaf(cf[j], w[16 + k - j], acc[k]);
        }
    }

    float4 o0, o1;
    o0.x = l2u_f(-acc[0]); o0.y = l2u_f(-acc[1]);
    o0.z = l2u_f(-acc[2]); o0.w = l2u_f(-acc[3]);
    o1.x = l2u_f(-acc[4]); o1.y = l2u_f(-acc[5]);
    o1.z = l2u_f(-acc[6]); o1.w = l2u_f(-acc[7]);
    *(float4*)(out_r + t0)     = o0;
    *(float4*)(out_r + t0 + 4) = o1;
}

extern "C" void kernel_launch(void* const* d_in, const int* in_sizes, int n_in,
                              void* d_out, int out_size, void* d_ws, size_t ws_size,
                              hipStream_t stream) {
    const float* sig = (const float*)d_in[0];   // (2048, 2400, 1) f32
    const float* lpc = (const float*)d_in[1];   // (2048, 15, 16) f32
    float* out = (float*)d_out;                  // (2048, 2400, 1) f32

    const int batch  = in_sizes[0] / T_LEN;      // 2048
    const int total  = batch * CHUNKS;           // 614400 threads
    const int blocks = (total + 255) / 256;      // 2400 blocks
    diff_pred_kernel<<<blocks, 256, 0, stream>>>(sig, lpc, out);
}

// Round 4
// 78.031 us; speedup vs baseline: 1.0312x; 1.0312x over previous
//
#include <hip/hip_runtime.h>
#include <hip/hip_bf16.h>
#include <math.h>

#define T_LEN    2400
#define NTAPS    16
#define FRAME    160
#define NFRAMES  15
#define OPT      16                      // outputs per thread; 16 | 160 -> uniform frame per thread
#define CHUNKS   (T_LEN / OPT)           // 150 chunks per row
#define SCALE_C    (255.0f / 32768.0f)
#define SCALE_1_C  (32768.0f / 255.0f)

// u2l: s * (32768/255) * (2^(|u|/16) - 1)
__device__ __forceinline__ float u2l_f(float uv) {
    float u = uv - 128.0f;
    float a = fabsf(u);
    float m = SCALE_1_C * (exp2f(a * 0.0625f) - 1.0f);
    return copysignf(m, u);
}

// l2u: clip(128 + s*16*log2(1 + SCALE*|x|), 0, 255)
__device__ __forceinline__ float l2u_f(float x) {
    float a = fabsf(x);
    float u = 16.0f * log2f(fmaf(SCALE_C, a, 1.0f));
    u = copysignf(u, x);
    float r = 128.0f + u;
    return fminf(fmaxf(r, 0.0f), 255.0f);
}

__global__ __launch_bounds__(256) void diff_pred_kernel(
        const float* __restrict__ sig,
        const float* __restrict__ lpc,
        float* __restrict__ out) {
    const int gid = blockIdx.x * 256 + threadIdx.x;   // flat (row, chunk) index
    const int row = gid / CHUNKS;
    const int c   = gid - row * CHUNKS;               // chunk in row
    const int t0  = c * OPT;

    const float* sig_r = sig + (size_t)row * T_LEN;
    const float* lpc_r = lpc + (size_t)row * (NFRAMES * NTAPS);
    float*       out_r = out + (size_t)row * T_LEN;

    // coefficients for this chunk's frame (uniform across the 16 outputs)
    const int f = c / 10;                             // == t0 / FRAME
    const float4 c0 = *(const float4*)&lpc_r[f * NTAPS + 0];
    const float4 c1 = *(const float4*)&lpc_r[f * NTAPS + 4];
    const float4 c2 = *(const float4*)&lpc_r[f * NTAPS + 8];
    const float4 c3 = *(const float4*)&lpc_r[f * NTAPS + 12];
    const float cf[NTAPS] = {c0.x, c0.y, c0.z, c0.w, c1.x, c1.y, c1.z, c1.w,
                             c2.x, c2.y, c2.z, c2.w, c3.x, c3.y, c3.z, c3.w};

    // decoded window w[m] = xt[t0 - 16 + m], m = 0..31 (zeros for t < 0)
    // t0-16 = 16*(c-1) floats -> 64B-aligned; 8 x float4 global loads
    float w[32];
    if (c >= 1) {
        const float4* p = (const float4*)(sig_r + t0 - NTAPS);
        #pragma unroll
        for (int q = 0; q < 8; ++q) {
            float4 v = p[q];
            w[4 * q + 0] = u2l_f(v.x);
            w[4 * q + 1] = u2l_f(v.y);
            w[4 * q + 2] = u2l_f(v.z);
            w[4 * q + 3] = u2l_f(v.w);
        }
    } else {
        #pragma unroll
        for (int m = 0; m < NTAPS; ++m) w[m] = 0.0f;
        const float4* p = (const float4*)sig_r;       // t0 == 0
        #pragma unroll
        for (int q = 0; q < 4; ++q) {
            float4 v = p[q];
            w[16 + 4 * q + 0] = u2l_f(v.x);
            w[16 + 4 * q + 1] = u2l_f(v.y);
            w[16 + 4 * q + 2] = u2l_f(v.z);
            w[16 + 4 * q + 3] = u2l_f(v.w);
        }
    }

    // out[t0+k] = l2u(-sum_j cf[j] * xt[t0+k-j]),  xt[t0+k-j] = w[16+k-j]
    float acc[OPT];
    #pragma unroll
    for (int k = 0; k < OPT; ++k) acc[k] = 0.0f;
    #pragma unroll
    for (int j = 0; j < NTAPS; ++j) {
        #pragma unroll
        for (int k = 0; k < OPT; ++k) {
            acc[k] = fmaf(cf[j], w[16 + k - j], acc[k]);
        }
    }

    float4 o[4];
    #pragma unroll
    for (int q = 0; q < 4; ++q) {
        o[q].x = l2u_f(-acc[4 * q + 0]);
        o[q].y = l2u_f(-acc[4 * q + 1]);
        o[q].z = l2u_f(-acc[4 * q + 2]);
        o[q].w = l2u_f(-acc[4 * q + 3]);
        *(float4*)(out_r + t0 + 4 * q) = o[q];
    }
}

extern "C" void kernel_launch(void* const* d_in, const int* in_sizes, int n_in,
                              void* d_out, int out_size, void* d_ws, size_t ws_size,
                              hipStream_t stream) {
    const float* sig = (const float*)d_in[0];   // (2048, 2400, 1) f32
    const float* lpc = (const float*)d_in[1];   // (2048, 15, 16) f32
    float* out = (float*)d_out;                  // (2048, 2400, 1) f32

    const int batch  = in_sizes[0] / T_LEN;      // 2048
    const int total  = batch * CHUNKS;           // 307200 threads
    const int blocks = (total + 255) / 256;      // 1200 blocks
    diff_pred_kernel<<<blocks, 256, 0, stream>>>(sig, lpc, out);
}

// Round 5
// 77.872 us; speedup vs baseline: 1.0333x; 1.0020x over previous
//
#include <hip/hip_runtime.h>
#include <hip/hip_bf16.h>
#include <math.h>

#define T_LEN   2400
#define NTAPS   16
#define FRAME   160
#define NFRAMES 15
#define NGROUPS (T_LEN / 4)      // 600 float4 output groups per row
#define SCALE_C    (255.0f / 32768.0f)
#define SCALE_1_C  (32768.0f / 255.0f)

// u2l: s * (32768/255) * (exp(|u|/128 * ln256) - 1) == s * SCALE_1 * (2^(|u|/16) - 1)
__device__ __forceinline__ float u2l_f(float uv) {
    float u = uv - 128.0f;
    float a = fabsf(u);
    float m = SCALE_1_C * (exp2f(a * 0.0625f) - 1.0f);
    return copysignf(m, u);
}

// l2u: clip(128 + s*16*log2(1 + SCALE*|x|), 0, 255)
__device__ __forceinline__ float l2u_f(float x) {
    float a = fabsf(x);
    float u = 16.0f * log2f(fmaf(SCALE_C, a, 1.0f));
    u = copysignf(u, x);
    float r = 128.0f + u;
    return fminf(fmaxf(r, 0.0f), 255.0f);
}

// Best measured variant (R1, 77.64 us): one block per row, LDS-staged decode
// (each sample decoded exactly once), float4 LDS reads for the FIR.
// R2 (direct-global, 3x decode) = +2.8 us; R3 (direct-global, 2x decode) = +0.4 us.
__global__ __launch_bounds__(256) void diff_pred_kernel(
        const float* __restrict__ sig,
        const float* __restrict__ lpc,
        float* __restrict__ out) {
    // xt_s[t0 + m] == xt[t0 - 16 + m]  (16-zero left pad); 16B-aligned for float4 reads
    __shared__ __align__(16) float xt_s[NTAPS + T_LEN];    // 2416 floats
    __shared__ __align__(16) float lpc_s[NFRAMES * NTAPS]; // 240 floats

    const int b   = blockIdx.x;
    const int tid = threadIdx.x;

    const float* sig_b = sig + (size_t)b * T_LEN;
    const float* lpc_b = lpc + (size_t)b * (NFRAMES * NTAPS);

    if (tid < NTAPS) xt_s[tid] = 0.0f;
    if (tid < NFRAMES * NTAPS) lpc_s[tid] = lpc_b[tid];

    // Stage + decode signal: 600 float4 loads across 256 threads
    const float4* sig4 = (const float4*)sig_b;
    for (int i = tid; i < NGROUPS; i += 256) {
        float4 v = sig4[i];
        float4 d;
        d.x = u2l_f(v.x);
        d.y = u2l_f(v.y);
        d.z = u2l_f(v.z);
        d.w = u2l_f(v.w);
        *(float4*)&xt_s[NTAPS + 4 * i] = d;
    }
    __syncthreads();

    float4* out4 = (float4*)(out + (size_t)b * T_LEN);
    for (int i = tid; i < NGROUPS; i += 256) {
        const int t0 = 4 * i;
        const int f  = i / 40;            // frame index; uniform over the 4 outputs

        const float4 c0 = *(const float4*)&lpc_s[f * NTAPS + 0];
        const float4 c1 = *(const float4*)&lpc_s[f * NTAPS + 4];
        const float4 c2 = *(const float4*)&lpc_s[f * NTAPS + 8];
        const float4 c3 = *(const float4*)&lpc_s[f * NTAPS + 12];
        float c[NTAPS] = {c0.x, c0.y, c0.z, c0.w, c1.x, c1.y, c1.z, c1.w,
                          c2.x, c2.y, c2.z, c2.w, c3.x, c3.y, c3.z, c3.w};

        // 20-float window xt[t0-16 .. t0+3]: 5 x ds_read_b128 (16B-aligned)
        const float4 w0 = *(const float4*)&xt_s[t0 + 0];
        const float4 w1 = *(const float4*)&xt_s[t0 + 4];
        const float4 w2 = *(const float4*)&xt_s[t0 + 8];
        const float4 w3 = *(const float4*)&xt_s[t0 + 12];
        const float4 w4 = *(const float4*)&xt_s[t0 + 16];
        float w[20] = {w0.x, w0.y, w0.z, w0.w, w1.x, w1.y, w1.z, w1.w,
                       w2.x, w2.y, w2.z, w2.w, w3.x, w3.y, w3.z, w3.w,
                       w4.x, w4.y, w4.z, w4.w};

        // out[t0+k] uses xt[t0+k-j] = w[16+k-j]
        float acc[4] = {0.0f, 0.0f, 0.0f, 0.0f};
        #pragma unroll
        for (int j = 0; j < NTAPS; ++j) {
            #pragma unroll
            for (int k = 0; k < 4; ++k) {
                acc[k] = fmaf(c[j], w[16 + k - j], acc[k]);
            }
        }

        float4 o;
        o.x = l2u_f(-acc[0]);
        o.y = l2u_f(-acc[1]);
        o.z = l2u_f(-acc[2]);
        o.w = l2u_f(-acc[3]);
        out4[i] = o;
    }
}

extern "C" void kernel_launch(void* const* d_in, const int* in_sizes, int n_in,
                              void* d_out, int out_size, void* d_ws, size_t ws_size,
                              hipStream_t stream) {
    const float* sig = (const float*)d_in[0];   // (2048, 2400, 1) f32
    const float* lpc = (const float*)d_in[1];   // (2048, 15, 16) f32
    float* out = (float*)d_out;                  // (2048, 2400, 1) f32

    const int batch = in_sizes[0] / T_LEN;       // 2048
    diff_pred_kernel<<<batch, 256, 0, stream>>>(sig, lpc, out);
}